// Round 1
// baseline (1501.609 us; speedup 1.0000x reference)
//
#include <hip/hip_runtime.h>
#include <hip/hip_bf16.h>
#include <math.h>

// Problem constants
#define BB 512
#define SS 32
#define DD 256
#define HH 4
#define DHH 64
#define PP 3
#define EE 8
#define KTOP 2
#define HID 1024
#define TT (BB*SS)          // 16384
#define CAP 8192            // 2*T*K/E
#define TD ((size_t)TT*DD)  // 4194304

__device__ __forceinline__ float wred(float v) {
#pragma unroll
  for (int off = 32; off; off >>= 1) v += __shfl_xor(v, off, 64);
  return v;
}

__device__ __forceinline__ float f4c(const float4& f, int u) {
  return (u == 0) ? f.x : (u == 1) ? f.y : (u == 2) ? f.z : f.w;
}

// ---------------- LN1 ----------------
__global__ void k_ln(const float* __restrict__ x, const float* __restrict__ w,
                     const float* __restrict__ b, float* __restrict__ h) {
  int t = blockIdx.x * 4 + (threadIdx.x >> 6);
  int lane = threadIdx.x & 63;
  float4 xv = reinterpret_cast<const float4*>(x + (size_t)t * DD)[lane];
  float s1 = xv.x + xv.y + xv.z + xv.w;
  float s2 = xv.x*xv.x + xv.y*xv.y + xv.z*xv.z + xv.w*xv.w;
  s1 = wred(s1); s2 = wred(s2);
  float m = s1 * (1.f/256.f);
  float var = s2 * (1.f/256.f) - m*m;
  float rs = rsqrtf(var + 1e-6f);
  float4 wv = reinterpret_cast<const float4*>(w)[lane];
  float4 bv = reinterpret_cast<const float4*>(b)[lane];
  float4 o;
  o.x = (xv.x-m)*rs*wv.x + bv.x;
  o.y = (xv.y-m)*rs*wv.y + bv.y;
  o.z = (xv.z-m)*rs*wv.z + bv.z;
  o.w = (xv.w-m)*rs*wv.w + bv.w;
  reinterpret_cast<float4*>(h + (size_t)t * DD)[lane] = o;
}

// ---------------- positional attention (rank-1 in q) ----------------
__global__ void k_pos(const float* __restrict__ pos, const float* __restrict__ p1w,
                      const float* __restrict__ p1b, const float* __restrict__ p2w,
                      const float* __restrict__ p2b, const float* __restrict__ headw,
                      float* __restrict__ pa) {
  int b = blockIdx.x;
  int tid = threadIdx.x;  // 128 = 32 s * 4 h
  __shared__ float ph[HH][SS];
  __shared__ float ex[HH][SS];
  int s = tid >> 2, hd = tid & 3;
  const float* pp = pos + ((size_t)b * SS + s) * PP;
  float p0 = pp[0], p1 = pp[1], p2 = pp[2];
  float t0 = fmaxf(0.f, p0*p1w[0] + p1*p1w[3] + p2*p1w[6] + p1b[0]);
  float t1 = fmaxf(0.f, p0*p1w[1] + p1*p1w[4] + p2*p1w[7] + p1b[1]);
  float t2 = fmaxf(0.f, p0*p1w[2] + p1*p1w[5] + p2*p1w[8] + p1b[2]);
  float acc = 0.f;
#pragma unroll
  for (int c = 0; c < 32; ++c) {
    float pf = t0*p2w[c] + t1*p2w[32+c] + t2*p2w[64+c] + p2b[c];
    acc += pf * headw[c*4 + hd];
  }
  ph[hd][s] = acc;
  __syncthreads();
  if (tid < 4) {
    int h2 = tid;
    float mx = -1e30f;
    for (int j = 0; j < 32; ++j) mx = fmaxf(mx, -ph[h2][j]);
    float sum = 0.f;
    for (int j = 0; j < 32; ++j) { float e = expf(-ph[h2][j] - mx); ex[h2][j] = e; sum += e; }
    float inv = 1.f / sum;
    for (int j = 0; j < 32; ++j) pa[((size_t)b*HH + h2)*SS + j] = ex[h2][j] * inv;
  }
}

// ---------------- QKV GEMM: [T,256] x [256,768] ----------------
__global__ __launch_bounds__(256) void k_qkv(const float* __restrict__ h,
        const float* __restrict__ qw, const float* __restrict__ kw, const float* __restrict__ vw,
        float* __restrict__ q, float* __restrict__ k, float* __restrict__ v) {
  int m0 = blockIdx.x * 64;
  int n0 = blockIdx.y * 64;
  int wsel = n0 >> 8;
  int c0 = n0 & 255;
  const float* W = (wsel == 0) ? qw : (wsel == 1) ? kw : vw;
  float* OUT = (wsel == 0) ? q : (wsel == 1) ? k : v;
  __shared__ float As[64*20];
  __shared__ float Bs[16*64];
  int tid = threadIdx.x;
  int tr = tid >> 4, tc = tid & 15;
  float acc[4][4] = {};
  for (int k0 = 0; k0 < 256; k0 += 16) {
    {
      int r = tid >> 2, kk = (tid & 3) * 4;
      *reinterpret_cast<float4*>(&As[r*20 + kk]) =
        *reinterpret_cast<const float4*>(h + (size_t)(m0 + r)*DD + k0 + kk);
      int r2 = tid >> 4, cc = (tid & 15) * 4;
      *reinterpret_cast<float4*>(&Bs[r2*64 + cc]) =
        *reinterpret_cast<const float4*>(W + (size_t)(k0 + r2)*DD + c0 + cc);
    }
    __syncthreads();
#pragma unroll
    for (int kk4 = 0; kk4 < 4; ++kk4) {
      float4 a[4];
#pragma unroll
      for (int r = 0; r < 4; ++r)
        a[r] = *reinterpret_cast<float4*>(&As[(tr*4 + r)*20 + kk4*4]);
#pragma unroll
      for (int u = 0; u < 4; ++u) {
        float4 bv = *reinterpret_cast<float4*>(&Bs[(kk4*4 + u)*64 + tc*4]);
#pragma unroll
        for (int r = 0; r < 4; ++r) {
          float av = f4c(a[r], u);
          acc[r][0] += av*bv.x; acc[r][1] += av*bv.y;
          acc[r][2] += av*bv.z; acc[r][3] += av*bv.w;
        }
      }
    }
    __syncthreads();
  }
#pragma unroll
  for (int r = 0; r < 4; ++r) {
    int t = m0 + tr*4 + r;
    int b = t >> 5, s = t & 31;
    int cg = c0 + tc*4;
    int hd = cg >> 6, d2 = cg & 63;
    float4 ov = make_float4(acc[r][0], acc[r][1], acc[r][2], acc[r][3]);
    *reinterpret_cast<float4*>(OUT + (((size_t)b*HH + hd)*SS + s)*DHH + d2) = ov;
  }
}

// ---------------- attention core per (b,h) ----------------
__global__ __launch_bounds__(256) void k_attn(const float* __restrict__ q, const float* __restrict__ k,
        const float* __restrict__ v, const float* __restrict__ pa, const float* __restrict__ gate_p,
        float* __restrict__ o) {
  int bh = blockIdx.x;
  int b = bh >> 2, hd = bh & 3;
  __shared__ float qs[32][65];
  __shared__ float ks[32][65];
  __shared__ float vs[32][64];
  __shared__ float ssm[32][33];
  __shared__ float pas[32];
  int tid = threadIdx.x;
  const float* qb = q + (size_t)bh * (SS*DHH);
  const float* kb = k + (size_t)bh * (SS*DHH);
  const float* vb = v + (size_t)bh * (SS*DHH);
  for (int it = tid; it < 512; it += 256) {
    int row = it >> 4, col = (it & 15) * 4;
    float4 qv = *reinterpret_cast<const float4*>(qb + row*DHH + col);
    float4 kv = *reinterpret_cast<const float4*>(kb + row*DHH + col);
    float4 vv = *reinterpret_cast<const float4*>(vb + row*DHH + col);
    qs[row][col] = qv.x; qs[row][col+1] = qv.y; qs[row][col+2] = qv.z; qs[row][col+3] = qv.w;
    ks[row][col] = kv.x; ks[row][col+1] = kv.y; ks[row][col+2] = kv.z; ks[row][col+3] = kv.w;
    *reinterpret_cast<float4*>(&vs[row][col]) = vv;
  }
  if (tid < 32) pas[tid] = pa[(size_t)bh * SS + tid];
  __syncthreads();
#pragma unroll
  for (int rr = 0; rr < 4; ++rr) {
    int id = tid + 256*rr;
    int i = id >> 5, j = id & 31;
    float acc = 0.f;
#pragma unroll
    for (int d = 0; d < 64; ++d) acc += qs[i][d] * ks[j][d];
    ssm[i][j] = acc * 0.125f;
  }
  __syncthreads();
  float gs = 1.f / (1.f + expf(-gate_p[hd]));
  float ga = 1.f - gs;
  if (tid < 32) {
    int i = tid;
    float mx = -1e30f;
    for (int j = 0; j < 32; ++j) mx = fmaxf(mx, ssm[i][j]);
    float sum = 0.f;
    float ev[32];
#pragma unroll
    for (int j = 0; j < 32; ++j) { ev[j] = expf(ssm[i][j] - mx); sum += ev[j]; }
    float inv = 1.f / sum;
#pragma unroll
    for (int j = 0; j < 32; ++j) ssm[i][j] = ga * ev[j] * inv + gs * pas[j];
  }
  __syncthreads();
#pragma unroll
  for (int rr = 0; rr < 8; ++rr) {
    int id = tid + 256*rr;
    int i = id >> 6, d = id & 63;
    float acc = 0.f;
#pragma unroll
    for (int j = 0; j < 32; ++j) acc += ssm[i][j] * vs[j][d];
    o[((size_t)b*SS + i)*DD + hd*DHH + d] = acc;
  }
}

// ---------------- out-proj + residual ----------------
__global__ __launch_bounds__(256) void k_outproj(const float* __restrict__ A,
        const float* __restrict__ W, const float* __restrict__ bias,
        const float* __restrict__ x, float* __restrict__ out) {
  int m0 = blockIdx.x * 64;
  int c0 = blockIdx.y * 64;
  __shared__ float As[64*20];
  __shared__ float Bs[16*64];
  int tid = threadIdx.x;
  int tr = tid >> 4, tc = tid & 15;
  float acc[4][4] = {};
  for (int k0 = 0; k0 < 256; k0 += 16) {
    {
      int r = tid >> 2, kk = (tid & 3) * 4;
      *reinterpret_cast<float4*>(&As[r*20 + kk]) =
        *reinterpret_cast<const float4*>(A + (size_t)(m0 + r)*DD + k0 + kk);
      int r2 = tid >> 4, cc = (tid & 15) * 4;
      *reinterpret_cast<float4*>(&Bs[r2*64 + cc]) =
        *reinterpret_cast<const float4*>(W + (size_t)(k0 + r2)*DD + c0 + cc);
    }
    __syncthreads();
#pragma unroll
    for (int kk4 = 0; kk4 < 4; ++kk4) {
      float4 a[4];
#pragma unroll
      for (int r = 0; r < 4; ++r)
        a[r] = *reinterpret_cast<float4*>(&As[(tr*4 + r)*20 + kk4*4]);
#pragma unroll
      for (int u = 0; u < 4; ++u) {
        float4 bv = *reinterpret_cast<float4*>(&Bs[(kk4*4 + u)*64 + tc*4]);
#pragma unroll
        for (int r = 0; r < 4; ++r) {
          float av = f4c(a[r], u);
          acc[r][0] += av*bv.x; acc[r][1] += av*bv.y;
          acc[r][2] += av*bv.z; acc[r][3] += av*bv.w;
        }
      }
    }
    __syncthreads();
  }
#pragma unroll
  for (int r = 0; r < 4; ++r) {
    int t = m0 + tr*4 + r;
    size_t idx = (size_t)t*DD + c0 + tc*4;
    float4 xv = *reinterpret_cast<const float4*>(x + idx);
    float4 bv = *reinterpret_cast<const float4*>(bias + c0 + tc*4);
    float4 ov;
    ov.x = xv.x + acc[r][0] + bv.x;
    ov.y = xv.y + acc[r][1] + bv.y;
    ov.z = xv.z + acc[r][2] + bv.z;
    ov.w = xv.w + acc[r][3] + bv.w;
    *reinterpret_cast<float4*>(out + idx) = ov;
  }
}

// ---------------- LN2 + gate logits + top-2 ----------------
__global__ void k_gate(const float* __restrict__ xo, const float* __restrict__ w,
                       const float* __restrict__ b, const float* __restrict__ wg,
                       float* __restrict__ flat, int* __restrict__ topi, float* __restrict__ gates) {
  int t = blockIdx.x * 4 + (threadIdx.x >> 6);
  int lane = threadIdx.x & 63;
  float4 xv = reinterpret_cast<const float4*>(xo + (size_t)t * DD)[lane];
  float s1 = xv.x + xv.y + xv.z + xv.w;
  float s2 = xv.x*xv.x + xv.y*xv.y + xv.z*xv.z + xv.w*xv.w;
  s1 = wred(s1); s2 = wred(s2);
  float m = s1 * (1.f/256.f);
  float var = s2 * (1.f/256.f) - m*m;
  float rs = rsqrtf(var + 1e-6f);
  float4 wv = reinterpret_cast<const float4*>(w)[lane];
  float4 bv = reinterpret_cast<const float4*>(b)[lane];
  float4 fv;
  fv.x = (xv.x-m)*rs*wv.x + bv.x;
  fv.y = (xv.y-m)*rs*wv.y + bv.y;
  fv.z = (xv.z-m)*rs*wv.z + bv.z;
  fv.w = (xv.w-m)*rs*wv.w + bv.w;
  reinterpret_cast<float4*>(flat + (size_t)t * DD)[lane] = fv;
  float pe[8] = {};
  const float* wgp = wg + lane*4*EE;
#pragma unroll
  for (int dd = 0; dd < 4; ++dd) {
    float fd = f4c(fv, dd);
#pragma unroll
    for (int e2 = 0; e2 < 8; ++e2) pe[e2] += fd * wgp[dd*EE + e2];
  }
#pragma unroll
  for (int off = 32; off; off >>= 1) {
#pragma unroll
    for (int e2 = 0; e2 < 8; ++e2) pe[e2] += __shfl_xor(pe[e2], off, 64);
  }
  if (lane == 0) {
    float best = -1e30f, second = -1e30f; int bi = 0, si = 0;
#pragma unroll
    for (int e2 = 0; e2 < 8; ++e2) {
      float vv = pe[e2];
      if (vv > best) { second = best; si = bi; best = vv; bi = e2; }
      else if (vv > second) { second = vv; si = e2; }
    }
    float e1 = expf(second - best);
    float inv = 1.f / (1.f + e1);
    topi[t*2+0] = bi; topi[t*2+1] = si;
    gates[t*2+0] = inv; gates[t*2+1] = e1 * inv;
  }
}

// ---------------- dispatch: histogram, scan, position ----------------
__global__ void k_hist(const int* __restrict__ topi, int* __restrict__ bc) {
  __shared__ int cnt[EE];
  int tid = threadIdx.x;
  if (tid < EE) cnt[tid] = 0;
  __syncthreads();
  int e = topi[blockIdx.x*256 + tid];
  atomicAdd(&cnt[e], 1);
  __syncthreads();
  if (tid < EE) bc[blockIdx.x*EE + tid] = cnt[tid];
}

__global__ void k_scan(const int* __restrict__ bc, int* __restrict__ bo, int* __restrict__ cnt) {
  int e = threadIdx.x;
  if (e < EE) {
    int run = 0;
    for (int blk = 0; blk < 128; ++blk) { bo[blk*EE + e] = run; run += bc[blk*EE + e]; }
    cnt[e] = run;
  }
}

__global__ void k_disp(const int* __restrict__ topi, const float* __restrict__ gates,
                       const int* __restrict__ bo, int* __restrict__ ltok, float* __restrict__ lgate) {
  int tid = threadIdx.x;
  int i = blockIdx.x*256 + tid;
  int e = topi[i];
  int wv = tid >> 6, lane = tid & 63;
  __shared__ int wcnt[4][EE];
  unsigned long long lt = (1ull << lane) - 1ull;
  int prefix = 0;
#pragma unroll
  for (int ee = 0; ee < EE; ++ee) {
    unsigned long long mb = __ballot(e == ee);
    if (e == ee) prefix = __popcll(mb & lt);
    if (lane == 0) wcnt[wv][ee] = __popcll(mb);
  }
  __syncthreads();
  int off = bo[blockIdx.x*EE + e];
  for (int w2 = 0; w2 < wv; ++w2) off += wcnt[w2][e];
  int pos = off + prefix;
  if (pos < CAP) { ltok[e*CAP + pos] = i >> 1; lgate[e*CAP + pos] = gates[i]; }
}

// ---------------- fused expert FFN: 64-row tiles, D->HID(gelu)->D ----------------
#define A_STR 260
#define H_STR 132

__global__ __launch_bounds__(256, 1) void k_expert(
    const float* __restrict__ flat, const float* __restrict__ w1, const float* __restrict__ b1,
    const float* __restrict__ w2, const float* __restrict__ b2,
    const int* __restrict__ ltok, const float* __restrict__ lgate, const int* __restrict__ cnt,
    float* __restrict__ out) {
  int e = blockIdx.x >> 7;
  int rt = blockIdx.x & 127;
  int kept = cnt[e]; if (kept > CAP) kept = CAP;
  int r0 = rt * 64;
  if (r0 >= kept) return;
  extern __shared__ float lds[];
  float* As = lds;                 // 64*260
  float* h1s = As + 64*A_STR;      // 64*132
  float* wt = h1s + 64*H_STR;      // 8192 (shared w1/w2 tile)
  int* tokv = (int*)(wt + 8192);   // 64
  float* gtv = (float*)(tokv + 64);// 64
  int tid = threadIdx.x;
  int tr = tid >> 4, tc = tid & 15;
  if (tid < 64) {
    int rr = r0 + tid;
    int src = (rr < kept) ? rr : r0;
    tokv[tid] = ltok[e*CAP + src];
    gtv[tid] = (rr < kept) ? lgate[e*CAP + rr] : 0.f;
  }
  __syncthreads();
  for (int it = tid; it < 4096; it += 256) {
    int row = it >> 6, qq = (it & 63) * 4;
    *reinterpret_cast<float4*>(&As[row*A_STR + qq]) =
      *reinterpret_cast<const float4*>(flat + (size_t)tokv[row]*DD + qq);
  }
  float y[4][16] = {};
  const float* W1 = w1 + (size_t)e * DD * HID;
  const float* W2 = w2 + (size_t)e * HID * DD;
  const float* B1 = b1 + e * HID;
  const float* B2 = b2 + e * DD;
  __syncthreads();
  for (int hc = 0; hc < 8; ++hc) {
    float hacc[4][8] = {};
    for (int kc = 0; kc < 4; ++kc) {
      for (int it = tid; it < 2048; it += 256) {
        int kk = it >> 5, qq = (it & 31) * 4;
        *reinterpret_cast<float4*>(&wt[kk*128 + qq]) =
          *reinterpret_cast<const float4*>(W1 + (size_t)(kc*64 + kk)*HID + hc*128 + qq);
      }
      __syncthreads();
#pragma unroll
      for (int kk4 = 0; kk4 < 16; ++kk4) {
        float4 a[4];
#pragma unroll
        for (int r = 0; r < 4; ++r)
          a[r] = *reinterpret_cast<float4*>(&As[(tr*4 + r)*A_STR + kc*64 + kk4*4]);
#pragma unroll
        for (int u = 0; u < 4; ++u) {
          float4 w0 = *reinterpret_cast<float4*>(&wt[(kk4*4 + u)*128 + tc*4]);
          float4 w1v = *reinterpret_cast<float4*>(&wt[(kk4*4 + u)*128 + 64 + tc*4]);
#pragma unroll
          for (int r = 0; r < 4; ++r) {
            float av = f4c(a[r], u);
            hacc[r][0] += av*w0.x;  hacc[r][1] += av*w0.y;
            hacc[r][2] += av*w0.z;  hacc[r][3] += av*w0.w;
            hacc[r][4] += av*w1v.x; hacc[r][5] += av*w1v.y;
            hacc[r][6] += av*w1v.z; hacc[r][7] += av*w1v.w;
          }
        }
      }
      __syncthreads();
    }
    // bias + exact gelu -> h1s
    float4 bb0 = *reinterpret_cast<const float4*>(B1 + hc*128 + tc*4);
    float4 bb1 = *reinterpret_cast<const float4*>(B1 + hc*128 + 64 + tc*4);
#pragma unroll
    for (int r = 0; r < 4; ++r) {
      float vals[8];
      vals[0] = hacc[r][0] + bb0.x; vals[1] = hacc[r][1] + bb0.y;
      vals[2] = hacc[r][2] + bb0.z; vals[3] = hacc[r][3] + bb0.w;
      vals[4] = hacc[r][4] + bb1.x; vals[5] = hacc[r][5] + bb1.y;
      vals[6] = hacc[r][6] + bb1.z; vals[7] = hacc[r][7] + bb1.w;
#pragma unroll
      for (int j = 0; j < 8; ++j) {
        float xx = vals[j];
        vals[j] = 0.5f * xx * (1.f + erff(xx * 0.70710678118654752f));
      }
      int rb = (tr*4 + r)*H_STR;
      h1s[rb + tc*4 + 0] = vals[0]; h1s[rb + tc*4 + 1] = vals[1];
      h1s[rb + tc*4 + 2] = vals[2]; h1s[rb + tc*4 + 3] = vals[3];
      h1s[rb + 64 + tc*4 + 0] = vals[4]; h1s[rb + 64 + tc*4 + 1] = vals[5];
      h1s[rb + 64 + tc*4 + 2] = vals[6]; h1s[rb + 64 + tc*4 + 3] = vals[7];
    }
    __syncthreads();
    for (int kc2 = 0; kc2 < 4; ++kc2) {
      for (int it = tid; it < 2048; it += 256) {
        int kk = it >> 6, qq = (it & 63) * 4;
        *reinterpret_cast<float4*>(&wt[kk*256 + qq]) =
          *reinterpret_cast<const float4*>(W2 + (size_t)(hc*128 + kc2*32 + kk)*DD + qq);
      }
      __syncthreads();
#pragma unroll
      for (int kk4 = 0; kk4 < 8; ++kk4) {
        float4 a[4];
#pragma unroll
        for (int r = 0; r < 4; ++r)
          a[r] = *reinterpret_cast<float4*>(&h1s[(tr*4 + r)*H_STR + kc2*32 + kk4*4]);
#pragma unroll
        for (int u = 0; u < 4; ++u) {
          float4 wv0 = *reinterpret_cast<float4*>(&wt[(kk4*4 + u)*256 + 0   + tc*4]);
          float4 wv1 = *reinterpret_cast<float4*>(&wt[(kk4*4 + u)*256 + 64  + tc*4]);
          float4 wv2 = *reinterpret_cast<float4*>(&wt[(kk4*4 + u)*256 + 128 + tc*4]);
          float4 wv3 = *reinterpret_cast<float4*>(&wt[(kk4*4 + u)*256 + 192 + tc*4]);
#pragma unroll
          for (int r = 0; r < 4; ++r) {
            float av = f4c(a[r], u);
            y[r][0]  += av*wv0.x; y[r][1]  += av*wv0.y; y[r][2]  += av*wv0.z; y[r][3]  += av*wv0.w;
            y[r][4]  += av*wv1.x; y[r][5]  += av*wv1.y; y[r][6]  += av*wv1.z; y[r][7]  += av*wv1.w;
            y[r][8]  += av*wv2.x; y[r][9]  += av*wv2.y; y[r][10] += av*wv2.z; y[r][11] += av*wv2.w;
            y[r][12] += av*wv3.x; y[r][13] += av*wv3.y; y[r][14] += av*wv3.z; y[r][15] += av*wv3.w;
          }
        }
      }
      __syncthreads();
    }
  }
#pragma unroll
  for (int r = 0; r < 4; ++r) {
    int row = tr*4 + r;
    if (r0 + row < kept) {
      float g = gtv[row];
      float* op = out + (size_t)tokv[row] * DD;
#pragma unroll
      for (int g4 = 0; g4 < 4; ++g4) {
        float4 b2v = *reinterpret_cast<const float4*>(B2 + g4*64 + tc*4);
        atomicAdd(&op[g4*64 + tc*4 + 0], g*(y[r][g4*4+0] + b2v.x));
        atomicAdd(&op[g4*64 + tc*4 + 1], g*(y[r][g4*4+1] + b2v.y));
        atomicAdd(&op[g4*64 + tc*4 + 2], g*(y[r][g4*4+2] + b2v.z));
        atomicAdd(&op[g4*64 + tc*4 + 3], g*(y[r][g4*4+3] + b2v.w));
      }
    }
  }
}

extern "C" void kernel_launch(void* const* d_in, const int* in_sizes, int n_in,
                              void* d_out, int out_size, void* d_ws, size_t ws_size,
                              hipStream_t stream) {
  (void)in_sizes; (void)n_in; (void)out_size; (void)ws_size;
  const float* x    = (const float*)d_in[0];
  const float* pos  = (const float*)d_in[1];
  const float* ln1w = (const float*)d_in[2];
  const float* ln1b = (const float*)d_in[3];
  const float* ln2w = (const float*)d_in[4];
  const float* ln2b = (const float*)d_in[5];
  const float* qw   = (const float*)d_in[6];
  const float* kw   = (const float*)d_in[7];
  const float* vw   = (const float*)d_in[8];
  const float* p1w  = (const float*)d_in[9];
  const float* p1b  = (const float*)d_in[10];
  const float* p2w  = (const float*)d_in[11];
  const float* p2b  = (const float*)d_in[12];
  const float* headw= (const float*)d_in[13];
  const float* gatep= (const float*)d_in[15];
  const float* outw = (const float*)d_in[16];
  const float* outb = (const float*)d_in[17];
  const float* wg   = (const float*)d_in[18];
  const float* ew1  = (const float*)d_in[19];
  const float* eb1  = (const float*)d_in[20];
  const float* ew2  = (const float*)d_in[21];
  const float* eb2  = (const float*)d_in[22];
  float* out = (float*)d_out;

  float* wsf  = (float*)d_ws;
  float* hbuf = wsf;                 // TD floats; reused as attention-out 'o'
  float* qb   = wsf + TD;
  float* kb   = wsf + 2*TD;
  float* vb   = wsf + 3*TD;
  float* flat = wsf + 4*TD;
  float* pa   = wsf + 5*TD;          // B*H*S = 65536
  float* lgate= pa + 65536;          // E*CAP = 65536
  float* gates= lgate + 65536;       // T*K = 32768
  int* topi   = (int*)(gates + 32768); // 32768
  int* ltok   = topi + 32768;          // 65536
  int* bc     = ltok + 65536;          // 1024
  int* bo     = bc + 1024;             // 1024
  int* cnt    = bo + 1024;             // 8

  k_pos<<<dim3(BB), dim3(128), 0, stream>>>(pos, p1w, p1b, p2w, p2b, headw, pa);
  k_ln<<<dim3(TT/4), dim3(256), 0, stream>>>(x, ln1w, ln1b, hbuf);
  k_qkv<<<dim3(TT/64, 12), dim3(256), 0, stream>>>(hbuf, qw, kw, vw, qb, kb, vb);
  k_attn<<<dim3(BB*HH), dim3(256), 0, stream>>>(qb, kb, vb, pa, gatep, hbuf);
  k_outproj<<<dim3(TT/64, 4), dim3(256), 0, stream>>>(hbuf, outw, outb, x, out);
  k_gate<<<dim3(TT/4), dim3(256), 0, stream>>>(out, ln2w, ln2b, wg, flat, topi, gates);
  k_hist<<<dim3(128), dim3(256), 0, stream>>>(topi, bc);
  k_scan<<<dim3(1), dim3(64), 0, stream>>>(bc, bo, cnt);
  k_disp<<<dim3(128), dim3(256), 0, stream>>>(topi, gates, bo, ltok, lgate);
  size_t smem = (size_t)(64*A_STR + 64*H_STR + 8192 + 128) * sizeof(float);
  k_expert<<<dim3(EE*128), dim3(256), smem, stream>>>(flat, ew1, eb1, ew2, eb2,
                                                      ltok, lgate, cnt, out);
}

// Round 2
// 338.089 us; speedup vs baseline: 4.4415x; 4.4415x over previous
//
#include <hip/hip_runtime.h>
#include <hip/hip_bf16.h>
#include <math.h>

// Problem constants
#define BB 512
#define SS 32
#define DD 256
#define HH 4
#define DHH 64
#define PP 3
#define EE 8
#define KTOP 2
#define HID 1024
#define TT (BB*SS)          // 16384
#define CAP 8192            // 2*T*K/E
#define TD ((size_t)TT*DD)  // 4194304

typedef short short8 __attribute__((ext_vector_type(8)));
typedef float f32x4 __attribute__((ext_vector_type(4)));

__device__ __forceinline__ float wred(float v) {
#pragma unroll
  for (int off = 32; off; off >>= 1) v += __shfl_xor(v, off, 64);
  return v;
}

__device__ __forceinline__ float f4c(const float4& f, int u) {
  return (u == 0) ? f.x : (u == 1) ? f.y : (u == 2) ? f.z : f.w;
}

__device__ __forceinline__ unsigned short f2b(float f) {
  union { float f; unsigned u; } x; x.f = f;
  unsigned r = x.u + 0x7fffu + ((x.u >> 16) & 1u);
  return (unsigned short)(r >> 16);
}

// tanh-approx gelu (max |err| ~3e-3 in working range; well under 0.098 budget)
__device__ __forceinline__ float gelu_f(float x) {
  float t = 0.7978845608f * x + 0.0356774081f * x * x * x;
  t = fminf(10.f, fmaxf(-10.f, t));
  float e = __expf(2.f * t);
  float th = (e - 1.f) / (e + 1.f);
  return 0.5f * x * (1.f + th);
}

// ---------------- LN1 ----------------
__global__ void k_ln(const float* __restrict__ x, const float* __restrict__ w,
                     const float* __restrict__ b, float* __restrict__ h) {
  int t = blockIdx.x * 4 + (threadIdx.x >> 6);
  int lane = threadIdx.x & 63;
  float4 xv = reinterpret_cast<const float4*>(x + (size_t)t * DD)[lane];
  float s1 = xv.x + xv.y + xv.z + xv.w;
  float s2 = xv.x*xv.x + xv.y*xv.y + xv.z*xv.z + xv.w*xv.w;
  s1 = wred(s1); s2 = wred(s2);
  float m = s1 * (1.f/256.f);
  float var = s2 * (1.f/256.f) - m*m;
  float rs = rsqrtf(var + 1e-6f);
  float4 wv = reinterpret_cast<const float4*>(w)[lane];
  float4 bv = reinterpret_cast<const float4*>(b)[lane];
  float4 o;
  o.x = (xv.x-m)*rs*wv.x + bv.x;
  o.y = (xv.y-m)*rs*wv.y + bv.y;
  o.z = (xv.z-m)*rs*wv.z + bv.z;
  o.w = (xv.w-m)*rs*wv.w + bv.w;
  reinterpret_cast<float4*>(h + (size_t)t * DD)[lane] = o;
}

// ---------------- positional attention (rank-1 in q) ----------------
__global__ void k_pos(const float* __restrict__ pos, const float* __restrict__ p1w,
                      const float* __restrict__ p1b, const float* __restrict__ p2w,
                      const float* __restrict__ p2b, const float* __restrict__ headw,
                      float* __restrict__ pa) {
  int b = blockIdx.x;
  int tid = threadIdx.x;  // 128 = 32 s * 4 h
  __shared__ float ph[HH][SS];
  __shared__ float ex[HH][SS];
  int s = tid >> 2, hd = tid & 3;
  const float* pp = pos + ((size_t)b * SS + s) * PP;
  float p0 = pp[0], p1 = pp[1], p2 = pp[2];
  float t0 = fmaxf(0.f, p0*p1w[0] + p1*p1w[3] + p2*p1w[6] + p1b[0]);
  float t1 = fmaxf(0.f, p0*p1w[1] + p1*p1w[4] + p2*p1w[7] + p1b[1]);
  float t2 = fmaxf(0.f, p0*p1w[2] + p1*p1w[5] + p2*p1w[8] + p1b[2]);
  float acc = 0.f;
#pragma unroll
  for (int c = 0; c < 32; ++c) {
    float pf = t0*p2w[c] + t1*p2w[32+c] + t2*p2w[64+c] + p2b[c];
    acc += pf * headw[c*4 + hd];
  }
  ph[hd][s] = acc;
  __syncthreads();
  if (tid < 4) {
    int h2 = tid;
    float mx = -1e30f;
    for (int j = 0; j < 32; ++j) mx = fmaxf(mx, -ph[h2][j]);
    float sum = 0.f;
    for (int j = 0; j < 32; ++j) { float e = expf(-ph[h2][j] - mx); ex[h2][j] = e; sum += e; }
    float inv = 1.f / sum;
    for (int j = 0; j < 32; ++j) pa[((size_t)b*HH + h2)*SS + j] = ex[h2][j] * inv;
  }
}

// ---------------- QKV GEMM: [T,256] x [256,768] ----------------
__global__ __launch_bounds__(256) void k_qkv(const float* __restrict__ h,
        const float* __restrict__ qw, const float* __restrict__ kw, const float* __restrict__ vw,
        float* __restrict__ q, float* __restrict__ k, float* __restrict__ v) {
  int m0 = blockIdx.x * 64;
  int n0 = blockIdx.y * 64;
  int wsel = n0 >> 8;
  int c0 = n0 & 255;
  const float* W = (wsel == 0) ? qw : (wsel == 1) ? kw : vw;
  float* OUT = (wsel == 0) ? q : (wsel == 1) ? k : v;
  __shared__ float As[64*20];
  __shared__ float Bs[16*64];
  int tid = threadIdx.x;
  int tr = tid >> 4, tc = tid & 15;
  float acc[4][4] = {};
  for (int k0 = 0; k0 < 256; k0 += 16) {
    {
      int r = tid >> 2, kk = (tid & 3) * 4;
      *reinterpret_cast<float4*>(&As[r*20 + kk]) =
        *reinterpret_cast<const float4*>(h + (size_t)(m0 + r)*DD + k0 + kk);
      int r2 = tid >> 4, cc = (tid & 15) * 4;
      *reinterpret_cast<float4*>(&Bs[r2*64 + cc]) =
        *reinterpret_cast<const float4*>(W + (size_t)(k0 + r2)*DD + c0 + cc);
    }
    __syncthreads();
#pragma unroll
    for (int kk4 = 0; kk4 < 4; ++kk4) {
      float4 a[4];
#pragma unroll
      for (int r = 0; r < 4; ++r)
        a[r] = *reinterpret_cast<float4*>(&As[(tr*4 + r)*20 + kk4*4]);
#pragma unroll
      for (int u = 0; u < 4; ++u) {
        float4 bv = *reinterpret_cast<float4*>(&Bs[(kk4*4 + u)*64 + tc*4]);
#pragma unroll
        for (int r = 0; r < 4; ++r) {
          float av = f4c(a[r], u);
          acc[r][0] += av*bv.x; acc[r][1] += av*bv.y;
          acc[r][2] += av*bv.z; acc[r][3] += av*bv.w;
        }
      }
    }
    __syncthreads();
  }
#pragma unroll
  for (int r = 0; r < 4; ++r) {
    int t = m0 + tr*4 + r;
    int b = t >> 5, s = t & 31;
    int cg = c0 + tc*4;
    int hd = cg >> 6, d2 = cg & 63;
    float4 ov = make_float4(acc[r][0], acc[r][1], acc[r][2], acc[r][3]);
    *reinterpret_cast<float4*>(OUT + (((size_t)b*HH + hd)*SS + s)*DHH + d2) = ov;
  }
}

// ---------------- attention core per (b,h) ----------------
__global__ __launch_bounds__(256) void k_attn(const float* __restrict__ q, const float* __restrict__ k,
        const float* __restrict__ v, const float* __restrict__ pa, const float* __restrict__ gate_p,
        float* __restrict__ o) {
  int bh = blockIdx.x;
  int b = bh >> 2, hd = bh & 3;
  __shared__ float qs[32][65];
  __shared__ float ks[32][65];
  __shared__ float vs[32][64];
  __shared__ float ssm[32][33];
  __shared__ float pas[32];
  int tid = threadIdx.x;
  const float* qb = q + (size_t)bh * (SS*DHH);
  const float* kb = k + (size_t)bh * (SS*DHH);
  const float* vb = v + (size_t)bh * (SS*DHH);
  for (int it = tid; it < 512; it += 256) {
    int row = it >> 4, col = (it & 15) * 4;
    float4 qv = *reinterpret_cast<const float4*>(qb + row*DHH + col);
    float4 kv = *reinterpret_cast<const float4*>(kb + row*DHH + col);
    float4 vv = *reinterpret_cast<const float4*>(vb + row*DHH + col);
    qs[row][col] = qv.x; qs[row][col+1] = qv.y; qs[row][col+2] = qv.z; qs[row][col+3] = qv.w;
    ks[row][col] = kv.x; ks[row][col+1] = kv.y; ks[row][col+2] = kv.z; ks[row][col+3] = kv.w;
    *reinterpret_cast<float4*>(&vs[row][col]) = vv;
  }
  if (tid < 32) pas[tid] = pa[(size_t)bh * SS + tid];
  __syncthreads();
#pragma unroll
  for (int rr = 0; rr < 4; ++rr) {
    int id = tid + 256*rr;
    int i = id >> 5, j = id & 31;
    float acc = 0.f;
#pragma unroll
    for (int d = 0; d < 64; ++d) acc += qs[i][d] * ks[j][d];
    ssm[i][j] = acc * 0.125f;
  }
  __syncthreads();
  float gs = 1.f / (1.f + expf(-gate_p[hd]));
  float ga = 1.f - gs;
  if (tid < 32) {
    int i = tid;
    float mx = -1e30f;
    for (int j = 0; j < 32; ++j) mx = fmaxf(mx, ssm[i][j]);
    float sum = 0.f;
    float ev[32];
#pragma unroll
    for (int j = 0; j < 32; ++j) { ev[j] = expf(ssm[i][j] - mx); sum += ev[j]; }
    float inv = 1.f / sum;
#pragma unroll
    for (int j = 0; j < 32; ++j) ssm[i][j] = ga * ev[j] * inv + gs * pas[j];
  }
  __syncthreads();
#pragma unroll
  for (int rr = 0; rr < 8; ++rr) {
    int id = tid + 256*rr;
    int i = id >> 6, d = id & 63;
    float acc = 0.f;
#pragma unroll
    for (int j = 0; j < 32; ++j) acc += ssm[i][j] * vs[j][d];
    o[((size_t)b*SS + i)*DD + hd*DHH + d] = acc;
  }
}

// ---------------- out-proj + residual ----------------
__global__ __launch_bounds__(256) void k_outproj(const float* __restrict__ A,
        const float* __restrict__ W, const float* __restrict__ bias,
        const float* __restrict__ x, float* __restrict__ out) {
  int m0 = blockIdx.x * 64;
  int c0 = blockIdx.y * 64;
  __shared__ float As[64*20];
  __shared__ float Bs[16*64];
  int tid = threadIdx.x;
  int tr = tid >> 4, tc = tid & 15;
  float acc[4][4] = {};
  for (int k0 = 0; k0 < 256; k0 += 16) {
    {
      int r = tid >> 2, kk = (tid & 3) * 4;
      *reinterpret_cast<float4*>(&As[r*20 + kk]) =
        *reinterpret_cast<const float4*>(A + (size_t)(m0 + r)*DD + k0 + kk);
      int r2 = tid >> 4, cc = (tid & 15) * 4;
      *reinterpret_cast<float4*>(&Bs[r2*64 + cc]) =
        *reinterpret_cast<const float4*>(W + (size_t)(k0 + r2)*DD + c0 + cc);
    }
    __syncthreads();
#pragma unroll
    for (int kk4 = 0; kk4 < 4; ++kk4) {
      float4 a[4];
#pragma unroll
      for (int r = 0; r < 4; ++r)
        a[r] = *reinterpret_cast<float4*>(&As[(tr*4 + r)*20 + kk4*4]);
#pragma unroll
      for (int u = 0; u < 4; ++u) {
        float4 bv = *reinterpret_cast<float4*>(&Bs[(kk4*4 + u)*64 + tc*4]);
#pragma unroll
        for (int r = 0; r < 4; ++r) {
          float av = f4c(a[r], u);
          acc[r][0] += av*bv.x; acc[r][1] += av*bv.y;
          acc[r][2] += av*bv.z; acc[r][3] += av*bv.w;
        }
      }
    }
    __syncthreads();
  }
#pragma unroll
  for (int r = 0; r < 4; ++r) {
    int t = m0 + tr*4 + r;
    size_t idx = (size_t)t*DD + c0 + tc*4;
    float4 xv = *reinterpret_cast<const float4*>(x + idx);
    float4 bv = *reinterpret_cast<const float4*>(bias + c0 + tc*4);
    float4 ov;
    ov.x = xv.x + acc[r][0] + bv.x;
    ov.y = xv.y + acc[r][1] + bv.y;
    ov.z = xv.z + acc[r][2] + bv.z;
    ov.w = xv.w + acc[r][3] + bv.w;
    *reinterpret_cast<float4*>(out + idx) = ov;
  }
}

// ---------------- LN2 + gate logits + top-2 (fp32 routing, bf16 token emit) ----------------
__global__ void k_gate(const float* __restrict__ xo, const float* __restrict__ w,
                       const float* __restrict__ b, const float* __restrict__ wg,
                       unsigned short* __restrict__ flatb, int* __restrict__ topi,
                       float* __restrict__ gates) {
  int t = blockIdx.x * 4 + (threadIdx.x >> 6);
  int lane = threadIdx.x & 63;
  float4 xv = reinterpret_cast<const float4*>(xo + (size_t)t * DD)[lane];
  float s1 = xv.x + xv.y + xv.z + xv.w;
  float s2 = xv.x*xv.x + xv.y*xv.y + xv.z*xv.z + xv.w*xv.w;
  s1 = wred(s1); s2 = wred(s2);
  float m = s1 * (1.f/256.f);
  float var = s2 * (1.f/256.f) - m*m;
  float rs = rsqrtf(var + 1e-6f);
  float4 wv = reinterpret_cast<const float4*>(w)[lane];
  float4 bv = reinterpret_cast<const float4*>(b)[lane];
  float4 fv;
  fv.x = (xv.x-m)*rs*wv.x + bv.x;
  fv.y = (xv.y-m)*rs*wv.y + bv.y;
  fv.z = (xv.z-m)*rs*wv.z + bv.z;
  fv.w = (xv.w-m)*rs*wv.w + bv.w;
  ushort4 fb;
  fb.x = f2b(fv.x); fb.y = f2b(fv.y); fb.z = f2b(fv.z); fb.w = f2b(fv.w);
  *reinterpret_cast<ushort4*>(flatb + (size_t)t * DD + lane*4) = fb;
  float pe[8] = {};
  const float* wgp = wg + lane*4*EE;
#pragma unroll
  for (int dd = 0; dd < 4; ++dd) {
    float fd = f4c(fv, dd);
#pragma unroll
    for (int e2 = 0; e2 < 8; ++e2) pe[e2] += fd * wgp[dd*EE + e2];
  }
#pragma unroll
  for (int off = 32; off; off >>= 1) {
#pragma unroll
    for (int e2 = 0; e2 < 8; ++e2) pe[e2] += __shfl_xor(pe[e2], off, 64);
  }
  if (lane == 0) {
    float best = -1e30f, second = -1e30f; int bi = 0, si = 0;
#pragma unroll
    for (int e2 = 0; e2 < 8; ++e2) {
      float vv = pe[e2];
      if (vv > best) { second = best; si = bi; best = vv; bi = e2; }
      else if (vv > second) { second = vv; si = e2; }
    }
    float e1 = expf(second - best);
    float inv = 1.f / (1.f + e1);
    topi[t*2+0] = bi; topi[t*2+1] = si;
    gates[t*2+0] = inv; gates[t*2+1] = e1 * inv;
  }
}

// ---------------- dispatch: histogram, scan, position ----------------
__global__ void k_hist(const int* __restrict__ topi, int* __restrict__ bc) {
  __shared__ int cnt[EE];
  int tid = threadIdx.x;
  if (tid < EE) cnt[tid] = 0;
  __syncthreads();
  int e = topi[blockIdx.x*256 + tid];
  atomicAdd(&cnt[e], 1);
  __syncthreads();
  if (tid < EE) bc[blockIdx.x*EE + tid] = cnt[tid];
}

__global__ void k_scan(const int* __restrict__ bc, int* __restrict__ bo, int* __restrict__ cnt) {
  int e = threadIdx.x;
  if (e < EE) {
    int run = 0;
    for (int blk = 0; blk < 128; ++blk) { bo[blk*EE + e] = run; run += bc[blk*EE + e]; }
    cnt[e] = run;
  }
}

__global__ void k_disp(const int* __restrict__ topi, const float* __restrict__ gates,
                       const int* __restrict__ bo, int* __restrict__ ltok, float* __restrict__ lgate) {
  int tid = threadIdx.x;
  int i = blockIdx.x*256 + tid;
  int e = topi[i];
  int wv = tid >> 6, lane = tid & 63;
  __shared__ int wcnt[4][EE];
  unsigned long long lt = (1ull << lane) - 1ull;
  int prefix = 0;
#pragma unroll
  for (int ee = 0; ee < EE; ++ee) {
    unsigned long long mb = __ballot(e == ee);
    if (e == ee) prefix = __popcll(mb & lt);
    if (lane == 0) wcnt[wv][ee] = __popcll(mb);
  }
  __syncthreads();
  int off = bo[blockIdx.x*EE + e];
  for (int w2 = 0; w2 < wv; ++w2) off += wcnt[w2][e];
  int pos = off + prefix;
  if (pos < CAP) { ltok[e*CAP + pos] = i >> 1; lgate[e*CAP + pos] = gates[i]; }
}

// ---------------- weight fp32 -> bf16 fragment-linear conversion ----------------
// Fragment layout: tile (e, kt, nt) = 512 bf16 contiguous; within tile lane l
// (c=l&15, g=l>>4) holds 8 consecutive k: src[e][kt*32+g*8+j][nt*16+c], j=0..7.
__global__ void k_cvtw(const float* __restrict__ src, unsigned short* __restrict__ dst,
                       int K, int N) {
  int idx = blockIdx.x * 256 + threadIdx.x;
  int lane = idx & 63;
  int tile = idx >> 6;
  int ntn = N >> 4;
  int ntk = K >> 5;
  int e = tile / (ntk * ntn);
  int rem = tile - e * (ntk * ntn);
  int kt = rem / ntn;
  int nt = rem - kt * ntn;
  int g = lane >> 4, c = lane & 15;
  const float* s = src + ((size_t)e * K + kt*32 + g*8) * N + nt*16 + c;
  short8 frag;
#pragma unroll
  for (int j = 0; j < 8; ++j) frag[j] = (short)f2b(s[(size_t)j * N]);
  reinterpret_cast<short8*>(dst)[(size_t)tile * 64 + lane] = frag;
}

// ---------------- MFMA expert FFN: 64-token tiles, bf16, fused ----------------
__global__ __launch_bounds__(256, 2) void k_expert(
    const unsigned short* __restrict__ flatb, const unsigned short* __restrict__ w1s,
    const float* __restrict__ b1, const unsigned short* __restrict__ w2s,
    const float* __restrict__ b2,
    const int* __restrict__ ltok, const float* __restrict__ lgate,
    const int* __restrict__ cnt, float* __restrict__ out) {
  int e = blockIdx.x & 7;          // expert -> XCD pinning (L2 locality)
  int rt0 = blockIdx.x >> 3;       // 0..127
  int kept = cnt[e]; if (kept > CAP) kept = CAP;
  int r0 = rt0 * 64;
  if (r0 >= kept) return;
  __shared__ short8 AsV[64*32];    // 32KB token tile, XOR-swizzled 16B chunks
  __shared__ short8 H1V[64*16];    // 16KB h1 chunk (bf16), swizzled
  __shared__ int tokv[64];
  __shared__ float gtv[64];
  int tid = threadIdx.x;
  int lane = tid & 63;
  int w = tid >> 6;
  int c = lane & 15, g = lane >> 4;
  if (tid < 64) {
    int rr = r0 + tid;
    int src = (rr < kept) ? rr : r0;
    tokv[tid] = ltok[e*CAP + src];
    gtv[tid] = (rr < kept) ? lgate[e*CAP + rr] : 0.f;
  }
  __syncthreads();
  {
    const short8* fb = reinterpret_cast<const short8*>(flatb);
#pragma unroll
    for (int it = 0; it < 8; ++it) {
      int id = tid + it*256;
      int row = id >> 5, ch = id & 31;
      AsV[row*32 + (ch ^ (row & 7))] = fb[(size_t)tokv[row]*32 + ch];
    }
  }
  __syncthreads();
  f32x4 y[4][4] = {};
  const short8* w1v = reinterpret_cast<const short8*>(w1s);
  const short8* w2v = reinterpret_cast<const short8*>(w2s);
  for (int hc = 0; hc < 8; ++hc) {
    f32x4 hacc[4][2] = {};
#pragma unroll
    for (int kt = 0; kt < 8; ++kt) {
      short8 a[4];
#pragma unroll
      for (int rt = 0; rt < 4; ++rt) {
        int row = rt*16 + c;
        a[rt] = AsV[row*32 + (((kt*4 + g)) ^ (row & 7))];
      }
      short8 bf[2];
#pragma unroll
      for (int ct = 0; ct < 2; ++ct) {
        int nt = hc*8 + w*2 + ct;
        bf[ct] = w1v[(size_t)((e*8 + kt)*64 + nt)*64 + lane];
      }
#pragma unroll
      for (int ct = 0; ct < 2; ++ct)
#pragma unroll
        for (int rt = 0; rt < 4; ++rt)
          hacc[rt][ct] = __builtin_amdgcn_mfma_f32_16x16x32_bf16(a[rt], bf[ct], hacc[rt][ct], 0, 0, 0);
    }
    __syncthreads();  // previous GEMM2 done reading H1V
    {
      unsigned short* h1u = reinterpret_cast<unsigned short*>(H1V);
#pragma unroll
      for (int ct = 0; ct < 2; ++ct) {
        int col = w*32 + ct*16 + c;   // 0..127 within chunk
        float bb = b1[e*HID + hc*128 + col];
#pragma unroll
        for (int rt = 0; rt < 4; ++rt) {
#pragma unroll
          for (int q = 0; q < 4; ++q) {
            int row = rt*16 + g*4 + q;
            float vv = gelu_f(hacc[rt][ct][q] + bb);
            int ch = (col >> 3) ^ (row & 7);
            h1u[row*128 + ch*8 + (col & 7)] = f2b(vv);
          }
        }
      }
    }
    __syncthreads();
#pragma unroll
    for (int kt2 = 0; kt2 < 4; ++kt2) {
      short8 a2[4];
#pragma unroll
      for (int rt = 0; rt < 4; ++rt) {
        int row = rt*16 + c;
        a2[rt] = H1V[row*16 + ((kt2*4 + g) ^ (row & 7))];
      }
      short8 b2f[4];
#pragma unroll
      for (int ct = 0; ct < 4; ++ct) {
        int nt = w*4 + ct;
        b2f[ct] = w2v[(size_t)((e*32 + hc*4 + kt2)*16 + nt)*64 + lane];
      }
#pragma unroll
      for (int ct = 0; ct < 4; ++ct)
#pragma unroll
        for (int rt = 0; rt < 4; ++rt)
          y[rt][ct] = __builtin_amdgcn_mfma_f32_16x16x32_bf16(a2[rt], b2f[ct], y[rt][ct], 0, 0, 0);
    }
  }
  // epilogue: gate-scale + bias, atomic accumulate into out
  float bb2[4];
#pragma unroll
  for (int ct = 0; ct < 4; ++ct) bb2[ct] = b2[e*DD + w*64 + ct*16 + c];
#pragma unroll
  for (int rt = 0; rt < 4; ++rt) {
#pragma unroll
    for (int q = 0; q < 4; ++q) {
      int row = rt*16 + g*4 + q;
      if (r0 + row < kept) {
        float gt = gtv[row];
        float* op = out + (size_t)tokv[row]*DD;
#pragma unroll
        for (int ct = 0; ct < 4; ++ct) {
          int col = w*64 + ct*16 + c;
          atomicAdd(&op[col], gt*(y[rt][ct][q] + bb2[ct]));
        }
      }
    }
  }
}

extern "C" void kernel_launch(void* const* d_in, const int* in_sizes, int n_in,
                              void* d_out, int out_size, void* d_ws, size_t ws_size,
                              hipStream_t stream) {
  (void)in_sizes; (void)n_in; (void)out_size; (void)ws_size;
  const float* x    = (const float*)d_in[0];
  const float* pos  = (const float*)d_in[1];
  const float* ln1w = (const float*)d_in[2];
  const float* ln1b = (const float*)d_in[3];
  const float* ln2w = (const float*)d_in[4];
  const float* ln2b = (const float*)d_in[5];
  const float* qw   = (const float*)d_in[6];
  const float* kw   = (const float*)d_in[7];
  const float* vw   = (const float*)d_in[8];
  const float* p1w  = (const float*)d_in[9];
  const float* p1b  = (const float*)d_in[10];
  const float* p2w  = (const float*)d_in[11];
  const float* p2b  = (const float*)d_in[12];
  const float* headw= (const float*)d_in[13];
  const float* gatep= (const float*)d_in[15];
  const float* outw = (const float*)d_in[16];
  const float* outb = (const float*)d_in[17];
  const float* wg   = (const float*)d_in[18];
  const float* ew1  = (const float*)d_in[19];
  const float* eb1  = (const float*)d_in[20];
  const float* ew2  = (const float*)d_in[21];
  const float* eb2  = (const float*)d_in[22];
  float* out = (float*)d_out;

  float* wsf  = (float*)d_ws;
  float* hbuf = wsf;                 // TD floats; reused as attention-out 'o'
  float* qb   = wsf + TD;
  float* kb   = wsf + 2*TD;
  float* vb   = wsf + 3*TD;
  // region5 (TD floats = 16MB) repurposed: bf16 tokens + bf16 weights
  unsigned short* flatb = (unsigned short*)(wsf + 4*TD);  // T*256 = 8MB
  unsigned short* w1s   = flatb + TD;                     // E*256*1024 = 4MB
  unsigned short* w2s   = w1s + (size_t)EE*DD*HID;        // E*1024*256 = 4MB
  float* pa   = wsf + 5*TD;          // B*H*S = 65536
  float* lgate= pa + 65536;          // E*CAP = 65536
  float* gates= lgate + 65536;       // T*K = 32768
  int* topi   = (int*)(gates + 32768); // 32768
  int* ltok   = topi + 32768;          // 65536
  int* bc     = ltok + 65536;          // 1024
  int* bo     = bc + 1024;             // 1024
  int* cnt    = bo + 1024;             // 8

  k_cvtw<<<dim3(1024), dim3(256), 0, stream>>>(ew1, w1s, DD, HID);
  k_cvtw<<<dim3(1024), dim3(256), 0, stream>>>(ew2, w2s, HID, DD);
  k_pos<<<dim3(BB), dim3(128), 0, stream>>>(pos, p1w, p1b, p2w, p2b, headw, pa);
  k_ln<<<dim3(TT/4), dim3(256), 0, stream>>>(x, ln1w, ln1b, hbuf);
  k_qkv<<<dim3(TT/64, 12), dim3(256), 0, stream>>>(hbuf, qw, kw, vw, qb, kb, vb);
  k_attn<<<dim3(BB*HH), dim3(256), 0, stream>>>(qb, kb, vb, pa, gatep, hbuf);
  k_outproj<<<dim3(TT/64, 4), dim3(256), 0, stream>>>(hbuf, outw, outb, x, out);
  k_gate<<<dim3(TT/4), dim3(256), 0, stream>>>(out, ln2w, ln2b, wg, flatb, topi, gates);
  k_hist<<<dim3(128), dim3(256), 0, stream>>>(topi, bc);
  k_scan<<<dim3(1), dim3(64), 0, stream>>>(bc, bo, cnt);
  k_disp<<<dim3(128), dim3(256), 0, stream>>>(topi, gates, bo, ltok, lgate);
  k_expert<<<dim3(EE*128), dim3(256), 0, stream>>>(flatb, w1s, eb1, w2s, eb2,
                                                   ltok, lgate, cnt, out);
}

// Round 3
// 327.783 us; speedup vs baseline: 4.5811x; 1.0314x over previous
//
#include <hip/hip_runtime.h>
#include <hip/hip_bf16.h>
#include <math.h>

// Problem constants
#define BB 512
#define SS 32
#define DD 256
#define HH 4
#define DHH 64
#define PP 3
#define EE 8
#define KTOP 2
#define HID 1024
#define TT (BB*SS)          // 16384
#define CAP 8192            // 2*T*K/E
#define TD ((size_t)TT*DD)  // 4194304

typedef short short8 __attribute__((ext_vector_type(8)));
typedef float f32x4 __attribute__((ext_vector_type(4)));

__device__ __forceinline__ float wred(float v) {
#pragma unroll
  for (int off = 32; off; off >>= 1) v += __shfl_xor(v, off, 64);
  return v;
}

__device__ __forceinline__ float f4c(const float4& f, int u) {
  return (u == 0) ? f.x : (u == 1) ? f.y : (u == 2) ? f.z : f.w;
}

__device__ __forceinline__ unsigned short f2b(float f) {
  union { float f; unsigned u; } x; x.f = f;
  unsigned r = x.u + 0x7fffu + ((x.u >> 16) & 1u);
  return (unsigned short)(r >> 16);
}

// tanh-approx gelu (max |err| ~3e-3 in working range; well under 0.098 budget)
__device__ __forceinline__ float gelu_f(float x) {
  float t = 0.7978845608f * x + 0.0356774081f * x * x * x;
  t = fminf(10.f, fmaxf(-10.f, t));
  float e = __expf(2.f * t);
  float th = (e - 1.f) / (e + 1.f);
  return 0.5f * x * (1.f + th);
}

// ---------------- LN1 ----------------
__global__ void k_ln(const float* __restrict__ x, const float* __restrict__ w,
                     const float* __restrict__ b, float* __restrict__ h) {
  int t = blockIdx.x * 4 + (threadIdx.x >> 6);
  int lane = threadIdx.x & 63;
  float4 xv = reinterpret_cast<const float4*>(x + (size_t)t * DD)[lane];
  float s1 = xv.x + xv.y + xv.z + xv.w;
  float s2 = xv.x*xv.x + xv.y*xv.y + xv.z*xv.z + xv.w*xv.w;
  s1 = wred(s1); s2 = wred(s2);
  float m = s1 * (1.f/256.f);
  float var = s2 * (1.f/256.f) - m*m;
  float rs = rsqrtf(var + 1e-6f);
  float4 wv = reinterpret_cast<const float4*>(w)[lane];
  float4 bv = reinterpret_cast<const float4*>(b)[lane];
  float4 o;
  o.x = (xv.x-m)*rs*wv.x + bv.x;
  o.y = (xv.y-m)*rs*wv.y + bv.y;
  o.z = (xv.z-m)*rs*wv.z + bv.z;
  o.w = (xv.w-m)*rs*wv.w + bv.w;
  reinterpret_cast<float4*>(h + (size_t)t * DD)[lane] = o;
}

// ---------------- positional attention (rank-1 in q) ----------------
__global__ void k_pos(const float* __restrict__ pos, const float* __restrict__ p1w,
                      const float* __restrict__ p1b, const float* __restrict__ p2w,
                      const float* __restrict__ p2b, const float* __restrict__ headw,
                      float* __restrict__ pa) {
  int b = blockIdx.x;
  int tid = threadIdx.x;  // 128 = 32 s * 4 h
  __shared__ float ph[HH][SS];
  __shared__ float ex[HH][SS];
  int s = tid >> 2, hd = tid & 3;
  const float* pp = pos + ((size_t)b * SS + s) * PP;
  float p0 = pp[0], p1 = pp[1], p2 = pp[2];
  float t0 = fmaxf(0.f, p0*p1w[0] + p1*p1w[3] + p2*p1w[6] + p1b[0]);
  float t1 = fmaxf(0.f, p0*p1w[1] + p1*p1w[4] + p2*p1w[7] + p1b[1]);
  float t2 = fmaxf(0.f, p0*p1w[2] + p1*p1w[5] + p2*p1w[8] + p1b[2]);
  float acc = 0.f;
#pragma unroll
  for (int c = 0; c < 32; ++c) {
    float pf = t0*p2w[c] + t1*p2w[32+c] + t2*p2w[64+c] + p2b[c];
    acc += pf * headw[c*4 + hd];
  }
  ph[hd][s] = acc;
  __syncthreads();
  if (tid < 4) {
    int h2 = tid;
    float mx = -1e30f;
    for (int j = 0; j < 32; ++j) mx = fmaxf(mx, -ph[h2][j]);
    float sum = 0.f;
    for (int j = 0; j < 32; ++j) { float e = expf(-ph[h2][j] - mx); ex[h2][j] = e; sum += e; }
    float inv = 1.f / sum;
    for (int j = 0; j < 32; ++j) pa[((size_t)b*HH + h2)*SS + j] = ex[h2][j] * inv;
  }
}

// ---------------- QKV GEMM: [T,256] x [256,768] ----------------
__global__ __launch_bounds__(256) void k_qkv(const float* __restrict__ h,
        const float* __restrict__ qw, const float* __restrict__ kw, const float* __restrict__ vw,
        float* __restrict__ q, float* __restrict__ k, float* __restrict__ v) {
  int m0 = blockIdx.x * 64;
  int n0 = blockIdx.y * 64;
  int wsel = n0 >> 8;
  int c0 = n0 & 255;
  const float* W = (wsel == 0) ? qw : (wsel == 1) ? kw : vw;
  float* OUT = (wsel == 0) ? q : (wsel == 1) ? k : v;
  __shared__ float As[64*20];
  __shared__ float Bs[16*64];
  int tid = threadIdx.x;
  int tr = tid >> 4, tc = tid & 15;
  float acc[4][4] = {};
  for (int k0 = 0; k0 < 256; k0 += 16) {
    {
      int r = tid >> 2, kk = (tid & 3) * 4;
      *reinterpret_cast<float4*>(&As[r*20 + kk]) =
        *reinterpret_cast<const float4*>(h + (size_t)(m0 + r)*DD + k0 + kk);
      int r2 = tid >> 4, cc = (tid & 15) * 4;
      *reinterpret_cast<float4*>(&Bs[r2*64 + cc]) =
        *reinterpret_cast<const float4*>(W + (size_t)(k0 + r2)*DD + c0 + cc);
    }
    __syncthreads();
#pragma unroll
    for (int kk4 = 0; kk4 < 4; ++kk4) {
      float4 a[4];
#pragma unroll
      for (int r = 0; r < 4; ++r)
        a[r] = *reinterpret_cast<float4*>(&As[(tr*4 + r)*20 + kk4*4]);
#pragma unroll
      for (int u = 0; u < 4; ++u) {
        float4 bv = *reinterpret_cast<float4*>(&Bs[(kk4*4 + u)*64 + tc*4]);
#pragma unroll
        for (int r = 0; r < 4; ++r) {
          float av = f4c(a[r], u);
          acc[r][0] += av*bv.x; acc[r][1] += av*bv.y;
          acc[r][2] += av*bv.z; acc[r][3] += av*bv.w;
        }
      }
    }
    __syncthreads();
  }
#pragma unroll
  for (int r = 0; r < 4; ++r) {
    int t = m0 + tr*4 + r;
    int b = t >> 5, s = t & 31;
    int cg = c0 + tc*4;
    int hd = cg >> 6, d2 = cg & 63;
    float4 ov = make_float4(acc[r][0], acc[r][1], acc[r][2], acc[r][3]);
    *reinterpret_cast<float4*>(OUT + (((size_t)b*HH + hd)*SS + s)*DHH + d2) = ov;
  }
}

// ---------------- attention core per (b,h) ----------------
__global__ __launch_bounds__(256) void k_attn(const float* __restrict__ q, const float* __restrict__ k,
        const float* __restrict__ v, const float* __restrict__ pa, const float* __restrict__ gate_p,
        float* __restrict__ o) {
  int bh = blockIdx.x;
  int b = bh >> 2, hd = bh & 3;
  __shared__ float qs[32][65];
  __shared__ float ks[32][65];
  __shared__ float vs[32][64];
  __shared__ float ssm[32][33];
  __shared__ float pas[32];
  int tid = threadIdx.x;
  const float* qb = q + (size_t)bh * (SS*DHH);
  const float* kb = k + (size_t)bh * (SS*DHH);
  const float* vb = v + (size_t)bh * (SS*DHH);
  for (int it = tid; it < 512; it += 256) {
    int row = it >> 4, col = (it & 15) * 4;
    float4 qv = *reinterpret_cast<const float4*>(qb + row*DHH + col);
    float4 kv = *reinterpret_cast<const float4*>(kb + row*DHH + col);
    float4 vv = *reinterpret_cast<const float4*>(vb + row*DHH + col);
    qs[row][col] = qv.x; qs[row][col+1] = qv.y; qs[row][col+2] = qv.z; qs[row][col+3] = qv.w;
    ks[row][col] = kv.x; ks[row][col+1] = kv.y; ks[row][col+2] = kv.z; ks[row][col+3] = kv.w;
    *reinterpret_cast<float4*>(&vs[row][col]) = vv;
  }
  if (tid < 32) pas[tid] = pa[(size_t)bh * SS + tid];
  __syncthreads();
#pragma unroll
  for (int rr = 0; rr < 4; ++rr) {
    int id = tid + 256*rr;
    int i = id >> 5, j = id & 31;
    float acc = 0.f;
#pragma unroll
    for (int d = 0; d < 64; ++d) acc += qs[i][d] * ks[j][d];
    ssm[i][j] = acc * 0.125f;
  }
  __syncthreads();
  float gs = 1.f / (1.f + expf(-gate_p[hd]));
  float ga = 1.f - gs;
  if (tid < 32) {
    int i = tid;
    float mx = -1e30f;
    for (int j = 0; j < 32; ++j) mx = fmaxf(mx, ssm[i][j]);
    float sum = 0.f;
    float ev[32];
#pragma unroll
    for (int j = 0; j < 32; ++j) { ev[j] = expf(ssm[i][j] - mx); sum += ev[j]; }
    float inv = 1.f / sum;
#pragma unroll
    for (int j = 0; j < 32; ++j) ssm[i][j] = ga * ev[j] * inv + gs * pas[j];
  }
  __syncthreads();
#pragma unroll
  for (int rr = 0; rr < 8; ++rr) {
    int id = tid + 256*rr;
    int i = id >> 6, d = id & 63;
    float acc = 0.f;
#pragma unroll
    for (int j = 0; j < 32; ++j) acc += ssm[i][j] * vs[j][d];
    o[((size_t)b*SS + i)*DD + hd*DHH + d] = acc;
  }
}

// ---------------- out-proj + residual ----------------
__global__ __launch_bounds__(256) void k_outproj(const float* __restrict__ A,
        const float* __restrict__ W, const float* __restrict__ bias,
        const float* __restrict__ x, float* __restrict__ out) {
  int m0 = blockIdx.x * 64;
  int c0 = blockIdx.y * 64;
  __shared__ float As[64*20];
  __shared__ float Bs[16*64];
  int tid = threadIdx.x;
  int tr = tid >> 4, tc = tid & 15;
  float acc[4][4] = {};
  for (int k0 = 0; k0 < 256; k0 += 16) {
    {
      int r = tid >> 2, kk = (tid & 3) * 4;
      *reinterpret_cast<float4*>(&As[r*20 + kk]) =
        *reinterpret_cast<const float4*>(A + (size_t)(m0 + r)*DD + k0 + kk);
      int r2 = tid >> 4, cc = (tid & 15) * 4;
      *reinterpret_cast<float4*>(&Bs[r2*64 + cc]) =
        *reinterpret_cast<const float4*>(W + (size_t)(k0 + r2)*DD + c0 + cc);
    }
    __syncthreads();
#pragma unroll
    for (int kk4 = 0; kk4 < 4; ++kk4) {
      float4 a[4];
#pragma unroll
      for (int r = 0; r < 4; ++r)
        a[r] = *reinterpret_cast<float4*>(&As[(tr*4 + r)*20 + kk4*4]);
#pragma unroll
      for (int u = 0; u < 4; ++u) {
        float4 bv = *reinterpret_cast<float4*>(&Bs[(kk4*4 + u)*64 + tc*4]);
#pragma unroll
        for (int r = 0; r < 4; ++r) {
          float av = f4c(a[r], u);
          acc[r][0] += av*bv.x; acc[r][1] += av*bv.y;
          acc[r][2] += av*bv.z; acc[r][3] += av*bv.w;
        }
      }
    }
    __syncthreads();
  }
#pragma unroll
  for (int r = 0; r < 4; ++r) {
    int t = m0 + tr*4 + r;
    size_t idx = (size_t)t*DD + c0 + tc*4;
    float4 xv = *reinterpret_cast<const float4*>(x + idx);
    float4 bv = *reinterpret_cast<const float4*>(bias + c0 + tc*4);
    float4 ov;
    ov.x = xv.x + acc[r][0] + bv.x;
    ov.y = xv.y + acc[r][1] + bv.y;
    ov.z = xv.z + acc[r][2] + bv.z;
    ov.w = xv.w + acc[r][3] + bv.w;
    *reinterpret_cast<float4*>(out + idx) = ov;
  }
}

// ---------------- LN2 + gate logits + top-2 (fp32 routing, bf16 token emit) ----------------
__global__ void k_gate(const float* __restrict__ xo, const float* __restrict__ w,
                       const float* __restrict__ b, const float* __restrict__ wg,
                       unsigned short* __restrict__ flatb, int* __restrict__ topi,
                       float* __restrict__ gates) {
  int t = blockIdx.x * 4 + (threadIdx.x >> 6);
  int lane = threadIdx.x & 63;
  float4 xv = reinterpret_cast<const float4*>(xo + (size_t)t * DD)[lane];
  float s1 = xv.x + xv.y + xv.z + xv.w;
  float s2 = xv.x*xv.x + xv.y*xv.y + xv.z*xv.z + xv.w*xv.w;
  s1 = wred(s1); s2 = wred(s2);
  float m = s1 * (1.f/256.f);
  float var = s2 * (1.f/256.f) - m*m;
  float rs = rsqrtf(var + 1e-6f);
  float4 wv = reinterpret_cast<const float4*>(w)[lane];
  float4 bv = reinterpret_cast<const float4*>(b)[lane];
  float4 fv;
  fv.x = (xv.x-m)*rs*wv.x + bv.x;
  fv.y = (xv.y-m)*rs*wv.y + bv.y;
  fv.z = (xv.z-m)*rs*wv.z + bv.z;
  fv.w = (xv.w-m)*rs*wv.w + bv.w;
  ushort4 fb;
  fb.x = f2b(fv.x); fb.y = f2b(fv.y); fb.z = f2b(fv.z); fb.w = f2b(fv.w);
  *reinterpret_cast<ushort4*>(flatb + (size_t)t * DD + lane*4) = fb;
  float pe[8] = {};
  const float* wgp = wg + lane*4*EE;
#pragma unroll
  for (int dd = 0; dd < 4; ++dd) {
    float fd = f4c(fv, dd);
#pragma unroll
    for (int e2 = 0; e2 < 8; ++e2) pe[e2] += fd * wgp[dd*EE + e2];
  }
#pragma unroll
  for (int off = 32; off; off >>= 1) {
#pragma unroll
    for (int e2 = 0; e2 < 8; ++e2) pe[e2] += __shfl_xor(pe[e2], off, 64);
  }
  if (lane == 0) {
    float best = -1e30f, second = -1e30f; int bi = 0, si = 0;
#pragma unroll
    for (int e2 = 0; e2 < 8; ++e2) {
      float vv = pe[e2];
      if (vv > best) { second = best; si = bi; best = vv; bi = e2; }
      else if (vv > second) { second = vv; si = e2; }
    }
    float e1 = expf(second - best);
    float inv = 1.f / (1.f + e1);
    topi[t*2+0] = bi; topi[t*2+1] = si;
    gates[t*2+0] = inv; gates[t*2+1] = e1 * inv;
  }
}

// ---------------- dispatch: histogram, scan, position ----------------
__global__ void k_hist(const int* __restrict__ topi, int* __restrict__ bc) {
  __shared__ int cnt[EE];
  int tid = threadIdx.x;
  if (tid < EE) cnt[tid] = 0;
  __syncthreads();
  int e = topi[blockIdx.x*256 + tid];
  atomicAdd(&cnt[e], 1);
  __syncthreads();
  if (tid < EE) bc[blockIdx.x*EE + tid] = cnt[tid];
}

__global__ void k_scan(const int* __restrict__ bc, int* __restrict__ bo, int* __restrict__ cnt) {
  int e = threadIdx.x;
  if (e < EE) {
    int run = 0;
    for (int blk = 0; blk < 128; ++blk) { bo[blk*EE + e] = run; run += bc[blk*EE + e]; }
    cnt[e] = run;
  }
}

__global__ void k_disp(const int* __restrict__ topi, const float* __restrict__ gates,
                       const int* __restrict__ bo, int* __restrict__ ltok, float* __restrict__ lgate) {
  int tid = threadIdx.x;
  int i = blockIdx.x*256 + tid;
  int e = topi[i];
  int wv = tid >> 6, lane = tid & 63;
  __shared__ int wcnt[4][EE];
  unsigned long long lt = (1ull << lane) - 1ull;
  int prefix = 0;
#pragma unroll
  for (int ee = 0; ee < EE; ++ee) {
    unsigned long long mb = __ballot(e == ee);
    if (e == ee) prefix = __popcll(mb & lt);
    if (lane == 0) wcnt[wv][ee] = __popcll(mb);
  }
  __syncthreads();
  int off = bo[blockIdx.x*EE + e];
  for (int w2 = 0; w2 < wv; ++w2) off += wcnt[w2][e];
  int pos = off + prefix;
  if (pos < CAP) { ltok[e*CAP + pos] = i >> 1; lgate[e*CAP + pos] = gates[i]; }
}

// ---------------- weight fp32 -> bf16 fragment-linear conversion ----------------
// Fragment layout: tile (e, kt, nt) = 512 bf16 contiguous; within tile lane l
// (c=l&15, g=l>>4) holds 8 consecutive k: src[e][kt*32+g*8+j][nt*16+c], j=0..7.
__global__ void k_cvtw(const float* __restrict__ src, unsigned short* __restrict__ dst,
                       int K, int N) {
  int idx = blockIdx.x * 256 + threadIdx.x;
  int lane = idx & 63;
  int tile = idx >> 6;
  int ntn = N >> 4;
  int ntk = K >> 5;
  int e = tile / (ntk * ntn);
  int rem = tile - e * (ntk * ntn);
  int kt = rem / ntn;
  int nt = rem - kt * ntn;
  int g = lane >> 4, c = lane & 15;
  const float* s = src + ((size_t)e * K + kt*32 + g*8) * N + nt*16 + c;
  short8 frag;
#pragma unroll
  for (int j = 0; j < 8; ++j) frag[j] = (short)f2b(s[(size_t)j * N]);
  reinterpret_cast<short8*>(dst)[(size_t)tile * 64 + lane] = frag;
}

// ---------------- MFMA expert FFN: 64-token tiles, bf16, LDS-staged weights ----------------
#define GLL(gp, lp) __builtin_amdgcn_global_load_lds( \
    (const __attribute__((address_space(1))) void*)(gp), \
    (__attribute__((address_space(3))) void*)(lp), 16, 0, 0)

// stage one 16KB B-chunk (16 fragment tiles of 1KB); wave w stages tiles w*4..w*4+3
#define STAGE1(HCC, KCC) do { \
  _Pragma("unroll") \
  for (int i_ = 0; i_ < 4; ++i_) { \
    int tt_ = w*4 + i_; \
    int gt_ = (e*8 + (KCC)*2 + (tt_>>3))*64 + (HCC)*8 + (tt_&7); \
    GLL(w1s + (size_t)gt_*512 + lane*8, (unsigned short*)(BbV + (buf^1)*1024 + tt_*64)); \
  } \
} while(0)

#define STAGE2(HCC, KC2) do { \
  _Pragma("unroll") \
  for (int i_ = 0; i_ < 4; ++i_) { \
    int tt_ = w*4 + i_; \
    int gt_ = (e*32 + (HCC)*4 + (KC2))*16 + tt_; \
    GLL(w2s + (size_t)gt_*512 + lane*8, (unsigned short*)(BbV + (buf^1)*1024 + tt_*64)); \
  } \
} while(0)

__global__ __launch_bounds__(256, 2) void k_expert(
    const unsigned short* __restrict__ flatb, const unsigned short* __restrict__ w1s,
    const float* __restrict__ b1, const unsigned short* __restrict__ w2s,
    const float* __restrict__ b2,
    const int* __restrict__ ltok, const float* __restrict__ lgate,
    const int* __restrict__ cnt, float* __restrict__ out) {
  int e = blockIdx.x & 7;          // expert -> XCD pinning (L2 locality)
  int rt0 = blockIdx.x >> 3;       // 0..127
  int kept = cnt[e]; if (kept > CAP) kept = CAP;
  int r0 = rt0 * 64;
  if (r0 >= kept) return;
  extern __shared__ char ldsraw[];
  short8* AsV = (short8*)ldsraw;   // 2048 short8 = 32KB token tile (swizzled)
  short8* H1V = AsV + 2048;        // 1024 short8 = 16KB h1 chunk (swizzled)
  short8* BbV = H1V + 1024;        // 2 x 1024 short8 = 32KB weight dbuf (linear)
  int tid = threadIdx.x;
  int lane = tid & 63;
  int w = tid >> 6;
  int c = lane & 15, g = lane >> 4;
  // ---- stage A: gather 64 token rows (bf16), XOR-swizzled 16B chunks
  {
    const short8* fb = reinterpret_cast<const short8*>(flatb);
#pragma unroll
    for (int it = 0; it < 8; ++it) {
      int id = tid + it*256;
      int row = id >> 5, ch = id & 31;
      int rr = r0 + row;
      int src = (rr < kept) ? rr : r0;
      int tok = ltok[e*CAP + src];
      AsV[row*32 + (ch ^ (row & 7))] = fb[(size_t)tok*32 + ch];
    }
  }
  int buf = 1;
  STAGE1(0, 0);        // prologue: stage first chunk into buffer 0
  __syncthreads();     // drains vmcnt -> chunk0 ready; A visible
  buf = 0;
  f32x4 y[4][4] = {};
  for (int hc = 0; hc < 8; ++hc) {
    f32x4 hacc[4][2] = {};
    // ---- GEMM1: 4 chunks of (K=64, N=128)
    for (int kc = 0; kc < 4; ++kc) {
      if (kc < 3) STAGE1(hc, kc+1);
      else        STAGE2(hc, 0);
#pragma unroll
      for (int ktl = 0; ktl < 2; ++ktl) {
        int kt = kc*2 + ktl;
        short8 a[4];
#pragma unroll
        for (int rt = 0; rt < 4; ++rt) {
          int row = rt*16 + c;
          a[rt] = AsV[row*32 + ((kt*4 + g) ^ (row & 7))];
        }
        short8 bfr[2];
#pragma unroll
        for (int ct = 0; ct < 2; ++ct)
          bfr[ct] = BbV[buf*1024 + (ktl*8 + w*2 + ct)*64 + lane];
#pragma unroll
        for (int ct = 0; ct < 2; ++ct)
#pragma unroll
          for (int rt = 0; rt < 4; ++rt)
            hacc[rt][ct] = __builtin_amdgcn_mfma_f32_16x16x32_bf16(a[rt], bfr[ct], hacc[rt][ct], 0, 0, 0);
      }
      __syncthreads();
      buf ^= 1;
    }
    // ---- bias + gelu -> H1V (bf16, swizzled)
    {
      unsigned short* h1u = reinterpret_cast<unsigned short*>(H1V);
#pragma unroll
      for (int ct = 0; ct < 2; ++ct) {
        int col = w*32 + ct*16 + c;   // 0..127 within chunk
        float bb = b1[e*HID + hc*128 + col];
#pragma unroll
        for (int rt = 0; rt < 4; ++rt) {
#pragma unroll
          for (int q = 0; q < 4; ++q) {
            int row = rt*16 + g*4 + q;
            float vv = gelu_f(hacc[rt][ct][q] + bb);
            int ch = (col >> 3) ^ (row & 7);
            h1u[row*128 + ch*8 + (col & 7)] = f2b(vv);
          }
        }
      }
    }
    __syncthreads();   // H1V visible to all waves
    // ---- GEMM2: 4 chunks of (K=32, N=256), accumulate into y
    for (int kc2 = 0; kc2 < 4; ++kc2) {
      if (kc2 < 3)      STAGE2(hc, kc2+1);
      else if (hc < 7)  STAGE1(hc+1, 0);
      short8 a2[4];
#pragma unroll
      for (int rt = 0; rt < 4; ++rt) {
        int row = rt*16 + c;
        a2[rt] = H1V[row*16 + ((kc2*4 + g) ^ (row & 7))];
      }
      short8 b2f[4];
#pragma unroll
      for (int ct = 0; ct < 4; ++ct)
        b2f[ct] = BbV[buf*1024 + (w*4 + ct)*64 + lane];
#pragma unroll
      for (int ct = 0; ct < 4; ++ct)
#pragma unroll
        for (int rt = 0; rt < 4; ++rt)
          y[rt][ct] = __builtin_amdgcn_mfma_f32_16x16x32_bf16(a2[rt], b2f[ct], y[rt][ct], 0, 0, 0);
      __syncthreads();
      buf ^= 1;
    }
  }
  // ---- epilogue: gate-scale + bias, atomic accumulate into out
  float bb2[4];
#pragma unroll
  for (int ct = 0; ct < 4; ++ct) bb2[ct] = b2[e*DD + w*64 + ct*16 + c];
#pragma unroll
  for (int rt = 0; rt < 4; ++rt) {
#pragma unroll
    for (int q = 0; q < 4; ++q) {
      int row = rt*16 + g*4 + q;
      int rr = r0 + row;
      if (rr < kept) {
        float gt = lgate[e*CAP + rr];
        int tok = ltok[e*CAP + rr];
        float* op = out + (size_t)tok*DD;
#pragma unroll
        for (int ct = 0; ct < 4; ++ct) {
          int col = w*64 + ct*16 + c;
          atomicAdd(&op[col], gt*(y[rt][ct][q] + bb2[ct]));
        }
      }
    }
  }
}

extern "C" void kernel_launch(void* const* d_in, const int* in_sizes, int n_in,
                              void* d_out, int out_size, void* d_ws, size_t ws_size,
                              hipStream_t stream) {
  (void)in_sizes; (void)n_in; (void)out_size; (void)ws_size;
  const float* x    = (const float*)d_in[0];
  const float* pos  = (const float*)d_in[1];
  const float* ln1w = (const float*)d_in[2];
  const float* ln1b = (const float*)d_in[3];
  const float* ln2w = (const float*)d_in[4];
  const float* ln2b = (const float*)d_in[5];
  const float* qw   = (const float*)d_in[6];
  const float* kw   = (const float*)d_in[7];
  const float* vw   = (const float*)d_in[8];
  const float* p1w  = (const float*)d_in[9];
  const float* p1b  = (const float*)d_in[10];
  const float* p2w  = (const float*)d_in[11];
  const float* p2b  = (const float*)d_in[12];
  const float* headw= (const float*)d_in[13];
  const float* gatep= (const float*)d_in[15];
  const float* outw = (const float*)d_in[16];
  const float* outb = (const float*)d_in[17];
  const float* wg   = (const float*)d_in[18];
  const float* ew1  = (const float*)d_in[19];
  const float* eb1  = (const float*)d_in[20];
  const float* ew2  = (const float*)d_in[21];
  const float* eb2  = (const float*)d_in[22];
  float* out = (float*)d_out;

  float* wsf  = (float*)d_ws;
  float* hbuf = wsf;                 // TD floats; reused as attention-out 'o'
  float* qb   = wsf + TD;
  float* kb   = wsf + 2*TD;
  float* vb   = wsf + 3*TD;
  // region5 (TD floats = 16MB) repurposed: bf16 tokens + bf16 weights
  unsigned short* flatb = (unsigned short*)(wsf + 4*TD);  // T*256 = 8MB
  unsigned short* w1s   = flatb + TD;                     // E*256*1024 = 4MB
  unsigned short* w2s   = w1s + (size_t)EE*DD*HID;        // E*1024*256 = 4MB
  float* pa   = wsf + 5*TD;          // B*H*S = 65536
  float* lgate= pa + 65536;          // E*CAP = 65536
  float* gates= lgate + 65536;       // T*K = 32768
  int* topi   = (int*)(gates + 32768); // 32768
  int* ltok   = topi + 32768;          // 65536
  int* bc     = ltok + 65536;          // 1024
  int* bo     = bc + 1024;             // 1024
  int* cnt    = bo + 1024;             // 8

  k_cvtw<<<dim3(1024), dim3(256), 0, stream>>>(ew1, w1s, DD, HID);
  k_cvtw<<<dim3(1024), dim3(256), 0, stream>>>(ew2, w2s, HID, DD);
  k_pos<<<dim3(BB), dim3(128), 0, stream>>>(pos, p1w, p1b, p2w, p2b, headw, pa);
  k_ln<<<dim3(TT/4), dim3(256), 0, stream>>>(x, ln1w, ln1b, hbuf);
  k_qkv<<<dim3(TT/64, 12), dim3(256), 0, stream>>>(hbuf, qw, kw, vw, qb, kb, vb);
  k_attn<<<dim3(BB*HH), dim3(256), 0, stream>>>(qb, kb, vb, pa, gatep, hbuf);
  k_outproj<<<dim3(TT/64, 4), dim3(256), 0, stream>>>(hbuf, outw, outb, x, out);
  k_gate<<<dim3(TT/4), dim3(256), 0, stream>>>(out, ln2w, ln2b, wg, flatb, topi, gates);
  k_hist<<<dim3(128), dim3(256), 0, stream>>>(topi, bc);
  k_scan<<<dim3(1), dim3(64), 0, stream>>>(bc, bo, cnt);
  k_disp<<<dim3(128), dim3(256), 0, stream>>>(topi, gates, bo, ltok, lgate);
  k_expert<<<dim3(EE*128), dim3(256), 81920, stream>>>(flatb, w1s, eb1, w2s, eb2,
                                                       ltok, lgate, cnt, out);
}